// Round 4
// baseline (101.413 us; speedup 1.0000x reference)
//
#include <hip/hip_runtime.h>
#include <hip/hip_bf16.h>
#include <math.h>

// ---------------- problem constants ----------------
#define N_ROWS 8192
#define DIM    512
#define NCLS   64
#define BM     256   // tile rows/cols (256^2 template)
#define BK     64    // K step
#define NKT    (DIM / BK)                    // 8 K-tiles
#define NTILE  (N_ROWS / BM)                 // 32 tile-blocks per side
#define NTRI   (NTILE * (NTILE + 1) / 2)     // 528 upper-tri tiles (= 8 * 66)
#define M_CONST 14.285714285714286f          // 1/0.07 == fixed max-shift (diagonal)
#define SCALE_SQRT 3.7796447300922722f       // sqrt(1/0.07): fold /T into operands

using bf16x8 = __attribute__((ext_vector_type(8))) short;
using f32x4  = __attribute__((ext_vector_type(4))) float;

static __device__ inline unsigned short f2bf(float x) {
  unsigned u = __float_as_uint(x);
  unsigned r = u + 0x7FFFu + ((u >> 16) & 1u);   // RNE
  return (unsigned short)(r >> 16);
}

// ---------------- kernel 1: L2-normalize rows, scale by sqrt(1/T), cast bf16 ----
__global__ __launch_bounds__(256) void normalize_rows(const float* __restrict__ proj,
                                                      unsigned short* __restrict__ outb) {
  const int row  = blockIdx.x * 4 + (threadIdx.x >> 6);
  const int lane = threadIdx.x & 63;
  const float4* src = (const float4*)(proj + (size_t)row * DIM);
  float4 a = src[lane * 2];
  float4 b = src[lane * 2 + 1];
  float ss = a.x*a.x + a.y*a.y + a.z*a.z + a.w*a.w
           + b.x*b.x + b.y*b.y + b.z*b.z + b.w*b.w;
#pragma unroll
  for (int off = 1; off < 64; off <<= 1) ss += __shfl_xor(ss, off);
  const float scale = SCALE_SQRT / fmaxf(sqrtf(ss), 1e-12f);
  float v[8] = {a.x, a.y, a.z, a.w, b.x, b.y, b.z, b.w};
  unsigned short h[8];
#pragma unroll
  for (int i = 0; i < 8; ++i) h[i] = f2bf(v[i] * scale);
  uint4 packed;
  packed.x = (unsigned)h[0] | ((unsigned)h[1] << 16);
  packed.y = (unsigned)h[2] | ((unsigned)h[3] << 16);
  packed.z = (unsigned)h[4] | ((unsigned)h[5] << 16);
  packed.w = (unsigned)h[6] | ((unsigned)h[7] << 16);
  *(uint4*)(outb + (size_t)row * DIM + lane * 8) = packed;
}

// ---------------- kernel 2: class histogram, wave-privatized ------------------
__global__ __launch_bounds__(1024) void class_hist(const int* __restrict__ tgt,
                                                   int* __restrict__ hist) {
  __shared__ int h[16][NCLS];
  const int wid = threadIdx.x >> 6;
  const int lane = threadIdx.x & 63;
  if (lane < NCLS) h[wid][lane] = 0;
  __syncthreads();
  for (int i = threadIdx.x; i < N_ROWS; i += 1024) atomicAdd(&h[wid][tgt[i]], 1);
  __syncthreads();
  if (threadIdx.x < NCLS) {
    int s = 0;
#pragma unroll
    for (int w = 0; w < 16; ++w) s += h[w][threadIdx.x];
    hist[threadIdx.x] = s;
  }
}

// ---------------- kernel 3: 256^2 phase-split tile GEMM + fused epilogue --------
// 528-block triangular grid (XCD-chunked, 528 = 8*66). 8 waves (2M x 4N), wave
// tile 128x64. LDS: 2 dbuf x (A 32KB + B 32KB) = 128KB, 1 block/CU. Per K-tile:
// B-frags register-resident (read once), 4 phases {A ds_read || half-tile
// global_load_lds prefetch -> raw s_barrier -> setprio(1) 16xMFMA setprio(0) ->
// raw s_barrier}. Prefetches stay in flight across intra-tile raw barriers;
// drained once per K-tile by the boundary __syncthreads (exactly when needed).
// Swizzle: 8x16B granules/row, key (r&7), applied global-source-side + read-side
// (global_load_lds dest must stay linear: wave-uniform base + lane*16).
__global__ __launch_bounds__(512, 2) void supcon_tile(const unsigned short* __restrict__ p16,
                                                      const int* __restrict__ tgt,
                                                      float* __restrict__ dpart,
                                                      float* __restrict__ spart) {
  // XCD-chunked bijective remap (528 % 8 == 0), then triangle decode
  const int logical = ((int)blockIdx.x & 7) * (NTRI / 8) + ((int)blockIdx.x >> 3);
  int rem = logical, br = 0;
  while (rem >= NTILE - br) { rem -= NTILE - br; ++br; }
  const int bc = br + rem;

  __shared__ short As[2][BM * BK];   // 2 x 32 KB
  __shared__ short Bs[2][BM * BK];   // 2 x 32 KB
  __shared__ int   tgr[BM], tgc[BM];
  __shared__ float redE[4][BM], redS[4][BM];   // row partials per wn
  __shared__ float redEc[2][BM], redSc[2][BM]; // col partials per wm

  const int tid  = threadIdx.x;
  const int lane = tid & 63;
  const int wid  = tid >> 6;          // 0..7
  const int wm = wid >> 2, wn = wid & 3;
  const int lhi = lane >> 4, llo = lane & 15;

  const size_t rowA0 = (size_t)br * BM;
  const size_t rowB0 = (size_t)bc * BM;

  // one half-tile (128 rows x 64 k = 16KB) = 2 global_load_lds per thread.
  // dst byte offset = h*16384 + g*16 (linear in lane); src granule pre-swizzled.
#define STAGE_HALF(XS, BUF, ROW0, H, KT) do {                                   \
  _Pragma("unroll")                                                             \
  for (int j = 0; j < 2; ++j) {                                                 \
    const int g  = wid * 64 + lane + j * 512;                                   \
    const int r  = (H) * 128 + (g >> 3);                                        \
    const int gl = (g & 7) ^ (r & 7);                                           \
    const unsigned short* src = p16 + ((ROW0) + r) * DIM + (KT) * BK + gl * 8;  \
    __builtin_amdgcn_global_load_lds(                                           \
        (const __attribute__((address_space(1))) void*)src,                     \
        (__attribute__((address_space(3))) void*)&XS[BUF][(H) * 8192 + g * 8],  \
        16, 0, 0);                                                              \
  }                                                                             \
} while (0)

  // prologue: stage K-tile 0 fully + targets
  STAGE_HALF(As, 0, rowA0, 0, 0);
  STAGE_HALF(As, 0, rowA0, 1, 0);
  STAGE_HALF(Bs, 0, rowB0, 0, 0);
  STAGE_HALF(Bs, 0, rowB0, 1, 0);
  if (tid < BM) tgr[tid] = tgt[br * BM + tid];
  else          tgc[tid - BM] = tgt[bc * BM + (tid - BM)];

  f32x4 zero = {0.f, 0.f, 0.f, 0.f};
  f32x4 acc[8][4];
#pragma unroll
  for (int i = 0; i < 8; ++i)
#pragma unroll
    for (int j = 0; j < 4; ++j) acc[i][j] = zero;

  __syncthreads();   // drains prologue stage (vmcnt(0))

  int cur = 0;
  for (int kt = 0; kt < NKT; ++kt) {
    const int nxt = cur ^ 1;
    const bool pf = (kt + 1 < NKT);

    // B-fragments for this K-tile: read once, hold in registers (8 x b128)
    bf16x8 bfr[4][2];
#pragma unroll
    for (int ni = 0; ni < 4; ++ni)
#pragma unroll
      for (int ks = 0; ks < 2; ++ks) {
        const int Rb = wn * 64 + ni * 16 + llo;
        bfr[ni][ks] = *(const bf16x8*)&Bs[cur][Rb * BK + (((ks * 4 + lhi) ^ (Rb & 7)) * 8)];
      }

#pragma unroll
    for (int ph = 0; ph < 4; ++ph) {
      const int h = ph >> 1, ks = ph & 1;
      bf16x8 af[4];
#pragma unroll
      for (int mi = 0; mi < 4; ++mi) {
        const int Ra = wm * 128 + h * 64 + mi * 16 + llo;
        af[mi] = *(const bf16x8*)&As[cur][Ra * BK + (((ks * 4 + lhi) ^ (Ra & 7)) * 8)];
      }
      if (pf) {   // one half-tile prefetch per phase (2 loads) into other buffer
        if (ph == 0)      STAGE_HALF(As, nxt, rowA0, 0, kt + 1);
        else if (ph == 1) STAGE_HALF(As, nxt, rowA0, 1, kt + 1);
        else if (ph == 2) STAGE_HALF(Bs, nxt, rowB0, 0, kt + 1);
        else              STAGE_HALF(Bs, nxt, rowB0, 1, kt + 1);
      }
      __builtin_amdgcn_s_barrier();        // lockstep; does NOT drain vmcnt
      __builtin_amdgcn_s_setprio(1);
#pragma unroll
      for (int mi = 0; mi < 4; ++mi)
#pragma unroll
        for (int ni = 0; ni < 4; ++ni)
          acc[h * 4 + mi][ni] =
              __builtin_amdgcn_mfma_f32_16x16x32_bf16(af[mi], bfr[ni][ks], acc[h * 4 + mi][ni], 0, 0, 0);
      __builtin_amdgcn_s_setprio(0);
      if (ph < 3) __builtin_amdgcn_s_barrier();
    }
    __syncthreads();   // K-tile boundary: drains prefetches exactly when needed
    cur = nxt;
  }
#undef STAGE_HALF

  // ---- epilogue: e = exp(sim - M) (self zeroed), s = sim if positive pair ----
  const bool diag = (br == bc);
  float ecol[4] = {0.f, 0.f, 0.f, 0.f};
  float scol[4] = {0.f, 0.f, 0.f, 0.f};

#pragma unroll
  for (int mi = 0; mi < 8; ++mi) {
#pragma unroll
    for (int rg = 0; rg < 4; ++rg) {
      const int rin  = wm * 128 + mi * 16 + lhi * 4 + rg;   // row within tile
      const int trow = tgr[rin];
      float esum = 0.f, ssum = 0.f;
#pragma unroll
      for (int ni = 0; ni < 4; ++ni) {
        const int cin = wn * 64 + ni * 16 + llo;            // col within tile
        const float sim = acc[mi][ni][rg];
        const bool self = diag && (rin == cin);
        const float e = self ? 0.f : __expf(sim - M_CONST);
        const bool pos = (!self) && (trow == tgc[cin]);
        const float sv = pos ? sim : 0.f;
        esum += e;  ssum += sv;
        ecol[ni] += e;  scol[ni] += sv;
      }
#pragma unroll
      for (int off = 1; off < 16; off <<= 1) {
        esum += __shfl_xor(esum, off);
        ssum += __shfl_xor(ssum, off);
      }
      if (llo == 0) { redE[wn][rin] = esum; redS[wn][rin] = ssum; }
    }
  }
  if (!diag) {
#pragma unroll
    for (int ni = 0; ni < 4; ++ni) {
      float ec = ecol[ni], sc = scol[ni];
      ec += __shfl_xor(ec, 16); ec += __shfl_xor(ec, 32);
      sc += __shfl_xor(sc, 16); sc += __shfl_xor(sc, 32);
      if (lhi == 0) {
        redEc[wm][wn * 64 + ni * 16 + llo] = ec;
        redSc[wm][wn * 64 + ni * 16 + llo] = sc;
      }
    }
  }
  __syncthreads();

  // cross-wave reduce + single write per [slot][row]; slots 0..31, each cell
  // written by exactly one block (row-path from (br,bc) under slot bc; col-path
  // under slot br) -> deterministic, no init needed.
  if (tid < BM) {
    const float e = redE[0][tid] + redE[1][tid] + redE[2][tid] + redE[3][tid];
    const float s = redS[0][tid] + redS[1][tid] + redS[2][tid] + redS[3][tid];
    dpart[(size_t)bc * N_ROWS + rowA0 + tid] = e;
    spart[(size_t)bc * N_ROWS + rowA0 + tid] = s;
  } else if (!diag) {
    const int c = tid - BM;
    dpart[(size_t)br * N_ROWS + rowB0 + c] = redEc[0][c] + redEc[1][c];
    spart[(size_t)br * N_ROWS + rowB0 + c] = redSc[0][c] + redSc[1][c];
  }
}

// ---------------- kernel 4: combine partials -> per-sample loss ----------------
__global__ __launch_bounds__(256) void combine_loss(const float* __restrict__ dpart,
                                                    const float* __restrict__ spart,
                                                    const int* __restrict__ tgt,
                                                    const int* __restrict__ hist,
                                                    float* __restrict__ out) {
  __shared__ float dsh[4][64], ssh[4][64];
  const int lane = threadIdx.x & 63;
  const int g    = threadIdx.x >> 6;
  const int r    = blockIdx.x * 64 + lane;
  float d = 0.f, s = 0.f;
  for (int k = g * 8; k < g * 8 + 8; ++k) {
    d += dpart[(size_t)k * N_ROWS + r];
    s += spart[(size_t)k * N_ROWS + r];
  }
  dsh[g][lane] = d; ssh[g][lane] = s;
  __syncthreads();
  if (g == 0) {
    d = dsh[0][lane] + dsh[1][lane] + dsh[2][lane] + dsh[3][lane];
    s = ssh[0][lane] + ssh[1][lane] + ssh[2][lane] + ssh[3][lane];
    const int cnt = hist[tgt[r]] - 1;
    out[r] = (cnt > 0) ? (s / (float)cnt - M_CONST - logf(d + 1e-8f)) : 0.f;
  }
}

// ---------------- launcher ----------------
extern "C" void kernel_launch(void* const* d_in, const int* in_sizes, int n_in,
                              void* d_out, int out_size, void* d_ws, size_t ws_size,
                              hipStream_t stream) {
  const float* proj = (const float*)d_in[0];
  const int*   tgt  = (const int*)d_in[1];
  float* out = (float*)d_out;

  char* ws = (char*)d_ws;
  unsigned short* p16  = (unsigned short*)ws;                        // 8 MB
  float* dpart = (float*)(ws + (size_t)8 * 1024 * 1024);             // 1 MB (32 x 8192)
  float* spart = (float*)(ws + (size_t)9 * 1024 * 1024);             // 1 MB
  int*   hist  = (int*)(ws + (size_t)10 * 1024 * 1024);              // 256 B

  normalize_rows<<<N_ROWS / 4, 256, 0, stream>>>(proj, p16);
  class_hist<<<1, 1024, 0, stream>>>(tgt, hist);
  supcon_tile<<<NTRI, 512, 0, stream>>>(p16, tgt, dpart, spart);
  combine_loss<<<N_ROWS / 64, 256, 0, stream>>>(dpart, spart, tgt, hist, out);
}